// Round 4
// baseline (567.001 us; speedup 1.0000x reference)
//
#include <hip/hip_runtime.h>
#include <hip/hip_cooperative_groups.h>

namespace cg = cooperative_groups;

#define G 4096
#define BROWS 8192
#define NBLK 1024
#define NTHR 256
#define NTILES 16384  // G*G / (NTHR*4)

typedef float f4 __attribute__((ext_vector_type(4)));  // native vector: OK for nontemporal builtins

// ws float offsets
#define OFF_PART 0         // part[256][4096] = 1048576 floats (4 MiB)
#define OFF_VMAG 1048576   // 4096 floats
#define OFF_PT   1052672   // 1024 floats
#define OFF_PN   1053696   // 1024 ints

// ---- phase bodies (shared between fused cooperative kernel and fallback) ----

// P1: per-stripe |velocity| column sums. b -> (col quarter, 32-row stripe).
__device__ __forceinline__ void phase_vmag_part(int b, int t,
                                                const float* __restrict__ vel,
                                                float* __restrict__ part) {
    const int bx = b & 3;
    const int by = b >> 2;  // 0..255 stripes of 32 rows
    const int col0 = bx * 1024 + t * 4;
    const float* p = vel + (size_t)by * 32 * G + col0;
    float ax = 0.f, ay = 0.f, az = 0.f, aw = 0.f;
#pragma unroll 8
    for (int r = 0; r < 32; ++r) {
        f4 v = __builtin_nontemporal_load((const f4*)p);
        ax += fabsf(v.x); ay += fabsf(v.y); az += fabsf(v.z); aw += fabsf(v.w);
        p += G;
    }
    f4 o = {ax, ay, az, aw};
    *(f4*)(part + (size_t)by * G + col0) = o;  // plain store
}

// P2: block b reduces col chunk [4b,4b+4) over 256 stripes via LDS tree.
__device__ __forceinline__ void phase_vmag_red(int b, int t,
                                               const float* __restrict__ part,
                                               float* __restrict__ vmag,
                                               f4* red) {
    f4 v = *(const f4*)(part + (size_t)t * G + b * 4);
    red[t] = v;
    __syncthreads();
    for (int off = NTHR / 2; off > 0; off >>= 1) {
        if (t < off) red[t] = red[t] + red[t + off];
        __syncthreads();
    }
    if (t == 0) {
        f4 a = red[0] * (1.0f / (float)BROWS);
        *(f4*)(vmag + b * 4) = a;
    }
}

// P3: grid-strided pairwise pass, register accumulation, one partial per block.
__device__ __forceinline__ void phase_pair(int b, int t,
                                           const float* __restrict__ adj,
                                           const float* __restrict__ vmag,
                                           float* __restrict__ pt,
                                           int* __restrict__ pn,
                                           float* st, int* sn) {
    float tt = 0.f;
    int nn = 0;
    for (int tile = b; tile < NTILES; tile += NBLK) {
        const size_t e = (size_t)tile * 1024 + t * 4;
        const int i = (int)(e >> 12);   // row (TF), uniform within tile
        const int j = (int)(e & 4095);  // col (target)
        const f4 a = __builtin_nontemporal_load((const f4*)(adj + e));
        const float vi = vmag[i];
        const f4 vj = *(const f4*)(vmag + j);
        if (a.x != 0.f) { tt += (a.x > 0.f) ? fabsf(vj.x - vi) : (vj.x + vi); ++nn; }
        if (a.y != 0.f) { tt += (a.y > 0.f) ? fabsf(vj.y - vi) : (vj.y + vi); ++nn; }
        if (a.z != 0.f) { tt += (a.z > 0.f) ? fabsf(vj.z - vi) : (vj.z + vi); ++nn; }
        if (a.w != 0.f) { tt += (a.w > 0.f) ? fabsf(vj.w - vi) : (vj.w + vi); ++nn; }
    }
#pragma unroll
    for (int off = 32; off > 0; off >>= 1) {
        tt += __shfl_down(tt, off);
        nn += __shfl_down(nn, off);
    }
    if ((t & 63) == 0) { st[t >> 6] = tt; sn[t >> 6] = nn; }
    __syncthreads();
    if (t == 0) {
        pt[b] = st[0] + st[1] + st[2] + st[3];
        pn[b] = sn[0] + sn[1] + sn[2] + sn[3];
    }
}

// P4: single block reduces the 1024 partials to the output scalar.
__device__ __forceinline__ void phase_final(int t,
                                            const float* __restrict__ pt,
                                            const int* __restrict__ pn,
                                            float* __restrict__ out,
                                            float* st, int* sn) {
    float s = 0.f;
    int n = 0;
    for (int k = t; k < NBLK; k += NTHR) { s += pt[k]; n += pn[k]; }
#pragma unroll
    for (int off = 32; off > 0; off >>= 1) {
        s += __shfl_down(s, off);
        n += __shfl_down(n, off);
    }
    if ((t & 63) == 0) { st[t >> 6] = s; sn[t >> 6] = n; }
    __syncthreads();
    if (t == 0) {
        const float tt = st[0] + st[1] + st[2] + st[3];
        const int nn = sn[0] + sn[1] + sn[2] + sn[3];
        out[0] = (nn > 0) ? (tt / fmaxf((float)nn, 1.f)) : 0.f;
    }
}

// ---- fused cooperative kernel: one dispatch, 3 grid syncs ----

__global__ __launch_bounds__(NTHR, 4) void fused(const float* __restrict__ vel,
                                                 const float* __restrict__ adj,
                                                 float* __restrict__ part,
                                                 float* __restrict__ vmag,
                                                 float* __restrict__ pt,
                                                 int* __restrict__ pn,
                                                 float* __restrict__ out) {
    __shared__ f4 red[NTHR];
    __shared__ float st[4];
    __shared__ int sn[4];
    cg::grid_group grid = cg::this_grid();
    const int t = threadIdx.x;
    const int b = blockIdx.x;

    phase_vmag_part(b, t, vel, part);
    grid.sync();
    phase_vmag_red(b, t, part, vmag, red);
    grid.sync();
    phase_pair(b, t, adj, vmag, pt, pn, st, sn);
    grid.sync();
    if (b == 0) phase_final(t, pt, pn, out, st, sn);
}

// ---- fallback: same phases as 4 plain kernels (if coop launch rejected) ----

__global__ __launch_bounds__(NTHR, 4) void k_vmag_part(const float* __restrict__ vel,
                                                       float* __restrict__ part) {
    phase_vmag_part(blockIdx.x, threadIdx.x, vel, part);
}

__global__ __launch_bounds__(NTHR, 4) void k_vmag_red(const float* __restrict__ part,
                                                      float* __restrict__ vmag) {
    __shared__ f4 red[NTHR];
    phase_vmag_red(blockIdx.x, threadIdx.x, part, vmag, red);
}

__global__ __launch_bounds__(NTHR, 4) void k_pair(const float* __restrict__ adj,
                                                  const float* __restrict__ vmag,
                                                  float* __restrict__ pt,
                                                  int* __restrict__ pn) {
    __shared__ float st[4];
    __shared__ int sn[4];
    phase_pair(blockIdx.x, threadIdx.x, adj, vmag, pt, pn, st, sn);
}

__global__ void k_final(const float* __restrict__ pt, const int* __restrict__ pn,
                        float* __restrict__ out) {
    __shared__ float st[4];
    __shared__ int sn[4];
    phase_final(threadIdx.x, pt, pn, out, st, sn);
}

// ---------------------------------------------------------------------------

extern "C" void kernel_launch(void* const* d_in, const int* in_sizes, int n_in,
                              void* d_out, int out_size, void* d_ws, size_t ws_size,
                              hipStream_t stream) {
    const float* vel = (const float*)d_in[0];
    // d_in[1] (perturbation_idx) unused by the reference.
    const float* adj = (const float*)d_in[2];
    float* wsf = (float*)d_ws;
    float* part = wsf + OFF_PART;
    float* vmag = wsf + OFF_VMAG;
    float* pt   = wsf + OFF_PT;
    int*   pn   = (int*)(wsf + OFF_PN);
    float* out  = (float*)d_out;

    void* args[] = {(void*)&vel, (void*)&adj, (void*)&part, (void*)&vmag,
                    (void*)&pt, (void*)&pn, (void*)&out};
    hipError_t err = hipLaunchCooperativeKernel(reinterpret_cast<void*>(fused),
                                                dim3(NBLK), dim3(NTHR), args, 0, stream);
    if (err != hipSuccess) {
        // deterministic fallback: identical phases, 4 dispatches
        k_vmag_part<<<NBLK, NTHR, 0, stream>>>(vel, part);
        k_vmag_red<<<NBLK, NTHR, 0, stream>>>(part, vmag);
        k_pair<<<NBLK, NTHR, 0, stream>>>(adj, vmag, pt, pn);
        k_final<<<1, NTHR, 0, stream>>>(pt, pn, out);
    }
}

// Round 5
// 281.495 us; speedup vs baseline: 2.0142x; 2.0142x over previous
//
#include <hip/hip_runtime.h>

#define G 4096
#define BROWS 8192
#define STRIPES 128        // 8192 rows / 64 rows per stripe
#define PAIR_BLOCKS 2048   // G*G / (256 thr * 4 elems * 8 tiles)
#define PAIR_TILES 16384   // G*G / (256 thr * 4 elems)

typedef float f4 __attribute__((ext_vector_type(4)));

// ws float offsets
#define OFF_PART 0                      // part[128][4096] = 524288 floats (2 MiB)
#define OFF_VMAG 524288                 // 4096 floats
#define OFF_PT   528384                 // 2048 floats
#define OFF_PN   530432                 // 2048 ints
#define OFF_CNT  532480                 // 1 uint (done counter)

// P1: per-64-row-stripe |velocity| column sums. Plain cached f4 loads.
__global__ __launch_bounds__(256) void vmag_partial(const float* __restrict__ vel,
                                                    float* __restrict__ part) {
    const int col0 = blockIdx.x * 1024 + threadIdx.x * 4;
    const int stripe = blockIdx.y;
    const float* p = vel + (size_t)stripe * 64 * G + col0;
    float ax = 0.f, ay = 0.f, az = 0.f, aw = 0.f;
#pragma unroll 8
    for (int r = 0; r < 64; ++r) {
        f4 v = *(const f4*)p;
        ax += fabsf(v.x); ay += fabsf(v.y); az += fabsf(v.z); aw += fabsf(v.w);
        p += G;
    }
    f4 o = {ax, ay, az, aw};
    *(f4*)(part + (size_t)stripe * G + col0) = o;  // plain store, no atomics
}

// P2: 32 blocks; block b reduces cols [b*128, b*128+128) over 128 stripes.
// thread t: c4 = t&31 (f4 col group), s0 = t>>5 (stripe slice of 16).
// Also zeroes the P3 done-counter (ws is poisoned 0xAA each call).
__global__ __launch_bounds__(256) void vmag_reduce(const float* __restrict__ part,
                                                   float* __restrict__ vmag,
                                                   unsigned int* __restrict__ counter) {
    if (blockIdx.x == 0 && threadIdx.x == 0) *counter = 0u;
    __shared__ f4 red[256];
    const int t = threadIdx.x;
    const int c4 = t & 31;
    const int s0 = t >> 5;
    const int col0 = blockIdx.x * 128 + c4 * 4;
    f4 acc = {0.f, 0.f, 0.f, 0.f};
#pragma unroll
    for (int k = 0; k < 16; ++k)
        acc += *(const f4*)(part + (size_t)(s0 + 8 * k) * G + col0);
    red[t] = acc;  // layout: red[s0*32 + c4]
    __syncthreads();
#pragma unroll
    for (int off = 128; off >= 32; off >>= 1) {
        if (t < off) red[t] += red[t + off];
        __syncthreads();
    }
    if (t < 32) {
        f4 a = red[t] * (1.0f / (float)BROWS);
        *(f4*)(vmag + blockIdx.x * 128 + t * 4) = a;
    }
}

// P3: pairwise pass (8 tiles/block) + last-block-done finalize.
__global__ __launch_bounds__(256) void pair_kernel(const float* __restrict__ adj,
                                                   const float* __restrict__ vmag,
                                                   float* __restrict__ pt,
                                                   int* __restrict__ pn,
                                                   unsigned int* __restrict__ counter,
                                                   float* __restrict__ out) {
    const int t = threadIdx.x;
    const int b = blockIdx.x;
    float tt = 0.f;
    int nn = 0;
#pragma unroll
    for (int k = 0; k < 8; ++k) {
        const int tile = b + k * PAIR_BLOCKS;
        const size_t e = (size_t)tile * 1024 + t * 4;
        const int i = tile >> 2;                       // wave-uniform row (TF)
        const int j = (tile & 3) * 1024 + t * 4;       // col (target)
        const f4 a = *(const f4*)(adj + e);
        const float vi = vmag[i];
        const f4 vj = *(const f4*)(vmag + j);
        if (a.x != 0.f) { tt += (a.x > 0.f) ? fabsf(vj.x - vi) : (vj.x + vi); ++nn; }
        if (a.y != 0.f) { tt += (a.y > 0.f) ? fabsf(vj.y - vi) : (vj.y + vi); ++nn; }
        if (a.z != 0.f) { tt += (a.z > 0.f) ? fabsf(vj.z - vi) : (vj.z + vi); ++nn; }
        if (a.w != 0.f) { tt += (a.w > 0.f) ? fabsf(vj.w - vi) : (vj.w + vi); ++nn; }
    }
#pragma unroll
    for (int off = 32; off > 0; off >>= 1) {
        tt += __shfl_down(tt, off);
        nn += __shfl_down(nn, off);
    }
    __shared__ float st[4];
    __shared__ int sn[4];
    if ((t & 63) == 0) { st[t >> 6] = tt; sn[t >> 6] = nn; }
    __syncthreads();
    __shared__ unsigned int s_old;
    if (t == 0) {
        pt[b] = st[0] + st[1] + st[2] + st[3];   // plain store
        pn[b] = sn[0] + sn[1] + sn[2] + sn[3];
        __threadfence();                          // release partials
        s_old = atomicAdd(counter, 1u);           // one device atomic per block
    }
    __syncthreads();
    if (s_old != PAIR_BLOCKS - 1) return;

    // ---- winner block: reduce all 2048 partials ----
    __threadfence();  // acquire
    float s = 0.f;
    int n = 0;
#pragma unroll
    for (int k = 0; k < PAIR_BLOCKS / 256; ++k) {
        s += pt[t + k * 256];
        n += pn[t + k * 256];
    }
#pragma unroll
    for (int off = 32; off > 0; off >>= 1) {
        s += __shfl_down(s, off);
        n += __shfl_down(n, off);
    }
    if ((t & 63) == 0) { st[t >> 6] = s; sn[t >> 6] = n; }
    __syncthreads();
    if (t == 0) {
        const float tot = st[0] + st[1] + st[2] + st[3];
        const int cnt = sn[0] + sn[1] + sn[2] + sn[3];
        out[0] = (cnt > 0) ? (tot / fmaxf((float)cnt, 1.f)) : 0.f;
    }
}

extern "C" void kernel_launch(void* const* d_in, const int* in_sizes, int n_in,
                              void* d_out, int out_size, void* d_ws, size_t ws_size,
                              hipStream_t stream) {
    const float* vel = (const float*)d_in[0];
    // d_in[1] (perturbation_idx) unused by the reference.
    const float* adj = (const float*)d_in[2];
    float* wsf = (float*)d_ws;
    float* part = wsf + OFF_PART;
    float* vmag = wsf + OFF_VMAG;
    float* pt   = wsf + OFF_PT;
    int*   pn   = (int*)(wsf + OFF_PN);
    unsigned int* counter = (unsigned int*)(wsf + OFF_CNT);
    float* out  = (float*)d_out;

    vmag_partial<<<dim3(4, STRIPES), 256, 0, stream>>>(vel, part);
    vmag_reduce<<<32, 256, 0, stream>>>(part, vmag, counter);
    pair_kernel<<<PAIR_BLOCKS, 256, 0, stream>>>(adj, vmag, pt, pn, counter, out);
}

// Round 6
// 235.126 us; speedup vs baseline: 2.4115x; 1.1972x over previous
//
#include <hip/hip_runtime.h>

#define G 4096
#define BROWS 8192
#define STRIPES 256        // 8192 rows / 32 rows per stripe
#define PAIR_BLOCKS 16384  // G*G / (256 thr * 4 elems)

typedef float f4 __attribute__((ext_vector_type(4)));

// ws float offsets
#define OFF_PART 0                      // part[256][4096] = 1048576 floats (4 MiB)
#define OFF_VMAG 1048576                // 4096 floats
#define OFF_PT   1052672                // 16384 floats
#define OFF_PN   1069056                // 16384 ints

// P1: per-32-row-stripe |velocity| column sums. 1024 blocks -> 16 waves/CU.
__global__ __launch_bounds__(256) void vmag_partial(const float* __restrict__ vel,
                                                    float* __restrict__ part) {
    const int col0 = (blockIdx.x & 3) * 1024 + threadIdx.x * 4;
    const int stripe = blockIdx.x >> 2;
    const float* p = vel + (size_t)stripe * 32 * G + col0;
    float ax = 0.f, ay = 0.f, az = 0.f, aw = 0.f;
#pragma unroll 8
    for (int r = 0; r < 32; ++r) {
        f4 v = *(const f4*)p;
        ax += fabsf(v.x); ay += fabsf(v.y); az += fabsf(v.z); aw += fabsf(v.w);
        p += G;
    }
    f4 o = {ax, ay, az, aw};
    *(f4*)(part + (size_t)stripe * G + col0) = o;  // plain store, no atomics
}

// P2: 32 blocks; block b reduces cols [b*128, b*128+128) over 256 stripes.
// thread t: c4 = t&31 (f4 col group), s0 = t>>5 (stripe slice); LDS tree.
__global__ __launch_bounds__(256) void vmag_reduce(const float* __restrict__ part,
                                                   float* __restrict__ vmag) {
    __shared__ f4 red[256];
    const int t = threadIdx.x;
    const int c4 = t & 31;
    const int s0 = t >> 5;
    const int col0 = blockIdx.x * 128 + c4 * 4;
    f4 acc = {0.f, 0.f, 0.f, 0.f};
#pragma unroll
    for (int k = 0; k < 32; ++k)
        acc += *(const f4*)(part + (size_t)(s0 + 8 * k) * G + col0);
    red[t] = acc;  // red[s0*32 + c4]
    __syncthreads();
#pragma unroll
    for (int off = 128; off >= 32; off >>= 1) {
        if (t < off) red[t] += red[t + off];
        __syncthreads();
    }
    if (t < 32) {
        f4 a = red[t] * (1.0f / (float)BROWS);
        *(f4*)(vmag + blockIdx.x * 128 + t * 4) = a;
    }
}

// P3: pairwise pass, 1 f4 per thread, plain partial store per block. No atomics.
__global__ __launch_bounds__(256) void pair_kernel(const float* __restrict__ adj,
                                                   const float* __restrict__ vmag,
                                                   float* __restrict__ pt,
                                                   int* __restrict__ pn) {
    const size_t e = ((size_t)blockIdx.x * 256 + threadIdx.x) * 4;
    const int i = (int)(e >> 12);   // row (TF), wave-uniform
    const int j = (int)(e & 4095);  // col (target)
    const f4 a = *(const f4*)(adj + e);
    const float vi = vmag[i];
    const f4 vj = *(const f4*)(vmag + j);

    float t = 0.f;
    int n = 0;
    if (a.x != 0.f) { t += (a.x > 0.f) ? fabsf(vj.x - vi) : (vj.x + vi); ++n; }
    if (a.y != 0.f) { t += (a.y > 0.f) ? fabsf(vj.y - vi) : (vj.y + vi); ++n; }
    if (a.z != 0.f) { t += (a.z > 0.f) ? fabsf(vj.z - vi) : (vj.z + vi); ++n; }
    if (a.w != 0.f) { t += (a.w > 0.f) ? fabsf(vj.w - vi) : (vj.w + vi); ++n; }

#pragma unroll
    for (int off = 32; off > 0; off >>= 1) {
        t += __shfl_down(t, off);
        n += __shfl_down(n, off);
    }
    __shared__ float st[4];
    __shared__ int sn[4];
    const int wave = threadIdx.x >> 6;
    if ((threadIdx.x & 63) == 0) { st[wave] = t; sn[wave] = n; }
    __syncthreads();
    if (threadIdx.x == 0) {
        pt[blockIdx.x] = st[0] + st[1] + st[2] + st[3];
        pn[blockIdx.x] = sn[0] + sn[1] + sn[2] + sn[3];
    }
}

// P4: one 1024-thread block reduces the 16384 partials.
__global__ __launch_bounds__(1024) void finalize_big(const float* __restrict__ pt,
                                                     const int* __restrict__ pn,
                                                     float* __restrict__ out) {
    float t = 0.f;
    int n = 0;
#pragma unroll
    for (int k = 0; k < PAIR_BLOCKS / 1024; ++k) {
        t += pt[threadIdx.x + k * 1024];
        n += pn[threadIdx.x + k * 1024];
    }
#pragma unroll
    for (int off = 32; off > 0; off >>= 1) {
        t += __shfl_down(t, off);
        n += __shfl_down(n, off);
    }
    __shared__ float st[16];
    __shared__ int sn[16];
    const int wave = threadIdx.x >> 6;
    if ((threadIdx.x & 63) == 0) { st[wave] = t; sn[wave] = n; }
    __syncthreads();
    if (threadIdx.x == 0) {
        float tt = 0.f;
        int nn = 0;
#pragma unroll
        for (int k = 0; k < 16; ++k) { tt += st[k]; nn += sn[k]; }
        out[0] = (nn > 0) ? (tt / fmaxf((float)nn, 1.f)) : 0.f;
    }
}

extern "C" void kernel_launch(void* const* d_in, const int* in_sizes, int n_in,
                              void* d_out, int out_size, void* d_ws, size_t ws_size,
                              hipStream_t stream) {
    const float* vel = (const float*)d_in[0];
    // d_in[1] (perturbation_idx) unused by the reference.
    const float* adj = (const float*)d_in[2];
    float* wsf = (float*)d_ws;
    float* part = wsf + OFF_PART;
    float* vmag = wsf + OFF_VMAG;
    float* pt   = wsf + OFF_PT;
    int*   pn   = (int*)(wsf + OFF_PN);
    float* out  = (float*)d_out;

    vmag_partial<<<1024, 256, 0, stream>>>(vel, part);
    vmag_reduce<<<32, 256, 0, stream>>>(part, vmag);
    pair_kernel<<<PAIR_BLOCKS, 256, 0, stream>>>(adj, vmag, pt, pn);
    finalize_big<<<1, 1024, 0, stream>>>(pt, pn, out);
}